// Round 15
// baseline (61.355 us; speedup 1.0000x reference)
//
#include <hip/hip_runtime.h>
#include <hip/hip_bf16.h>

#define N 1024
#define D 128
#define LEAK 0.2f

#define MROWS 4          // i-rows per mega block

// workspace layout (float offsets)
#define OFF_W2T  0
#define OFF_WPD  16384
#define OFF_WUT  16512
#define OFF_S1   16640
#define OFF_S2   17664
#define OFF_BASE 18688

// ---------------------------------------------------------------------------
// K_A: prep + base, v3 (byte-identical to round 14 — known-good).
__global__ __launch_bounds__(256) void prep_base_kernel(
    const float* __restrict__ W, const float* __restrict__ W1,
    const float* __restrict__ W2, const float* __restrict__ a,
    const float* __restrict__ h, const float* __restrict__ b1,
    float* __restrict__ W2t, float* __restrict__ wpd, float* __restrict__ wut,
    float* __restrict__ s1, float* __restrict__ s2, float* __restrict__ base) {
    __shared__ float pool[4160];
    __shared__ float red[4], red2[4];
    int b = blockIdx.x, tid = threadIdx.x;
    if (b < 512) {
        float* hl  = pool;          // [2][128]
        float* whl = pool + 256;    // [2][128]
        int i0 = b * 2;
        if (tid < 64) ((float4*)hl)[tid] = ((const float4*)(h + i0 * D))[tid];
        __syncthreads();
        int r = tid >> 7, l = tid & 127;
        float u = 0.f;
        #pragma unroll 8
        for (int q = 0; q < D; q += 4) {
            float4 hq = *(const float4*)&hl[r * D + q];
            float4 wq = *(const float4*)&W[l * D + q];
            u = fmaf(hq.x, wq.x, u); u = fmaf(hq.y, wq.y, u);
            u = fmaf(hq.z, wq.z, u); u = fmaf(hq.w, wq.w, u);
        }
        whl[r * D + l] = u;
        __syncthreads();
        {
            int w = tid >> 6, l63 = tid & 63;
            int row = w >> 1, half = w & 1;
            float wh = whl[row * D + half * 64 + l63];
            float p1 = wh * a[half * 64 + l63];
            float p2 = wh * a[D + half * 64 + l63];
            #pragma unroll
            for (int off = 32; off > 0; off >>= 1) {
                p1 += __shfl_xor(p1, off);
                p2 += __shfl_xor(p2, off);
            }
            if (l63 == 0) { red[w] = p1; red2[w] = p2; }
        }
        __syncthreads();
        if (tid < 2) {
            s1[i0 + tid] = red[2 * tid] + red[2 * tid + 1];
            s2[i0 + tid] = red2[2 * tid] + red2[2 * tid + 1];
        }
        float acc = b1[l];
        #pragma unroll 8
        for (int q = 0; q < D; q += 2) {
            float2 wh2 = *(const float2*)&whl[r * D + q];
            float2 x = *(const float2*)&W1[l * (D + 2) + q];
            acc = fmaf(wh2.x, x.x, acc);
            acc = fmaf(wh2.y, x.y, acc);
        }
        base[(i0 + r) * D + l] = acc;
    } else if (b < 516) {
        int kbase = 32 * (b - 512);
        #pragma unroll
        for (int p = 0; p < 16; p++) {
            int idx = tid + p * 256;
            int rd = idx >> 5, cc = idx & 31;
            pool[cc * 129 + rd] = W2[rd * D + kbase + cc];
        }
        __syncthreads();
        #pragma unroll
        for (int p = 0; p < 16; p++) {
            int idx = tid + p * 256;
            int kl = idx >> 7, dd = idx & 127;
            W2t[(kbase + kl) * D + dd] = pool[kl * 129 + dd];
        }
    } else {
        if (tid < 128) wpd[tid] = W1[tid * (D + 2) + D];
        else           wut[tid - 128] = W1[(tid - 128) * (D + 2) + D + 1];
    }
}

// ---------------------------------------------------------------------------
// K_B: mega v7 — 256 blocks x 512 thr, MROWS=4, one 4-k slice per thread.
//   16 groups x 32 lanes; step c: group g owns j = c*16+g (64 steps).
//   Group reads base[j][l32*4..] = full 512B row, coalesced; pd/ut/al are
//   32-lane broadcasts. Base L2 traffic: 256 x 512KB = 128MB (half of v5).
//   acc = 4 rows x 4 k = 16 VGPR; 4 blocks/CU (LDS 34KB) = 8 waves/SIMD.
__global__ __launch_bounds__(512, 8) void mega_kernel(
    const float* __restrict__ base, const float* __restrict__ s1,
    const float* __restrict__ s2, const int* __restrict__ adj,
    const float* __restrict__ pd, const float* __restrict__ ut,
    const float* __restrict__ wpd, const float* __restrict__ wut,
    const float* __restrict__ W2t, const float* __restrict__ b2,
    float* __restrict__ out) {
    __shared__ float al[MROWS][N];        // 16KB alpha
    __shared__ float racc[8][MROWS][D];   // 16KB wave partials
    __shared__ float red[8], red2[8], gsum[MROWS];
    __shared__ float tl[MROWS][D];        // 2KB

    const int tid = threadIdx.x;          // 0..511
    const int i0 = blockIdx.x * MROWS;

    // ---- phase 0: alpha (row r <-> 128 threads = waves 2r, 2r+1; 8 j/thread) ----
    {
        int r = tid >> 7;
        int i = i0 + r;
        int jb = (tid & 127) * 8;
        float s1i = s1[i];
        float4 sa = *(const float4*)&s2[jb];
        float4 sb = *(const float4*)&s2[jb + 4];
        int4 ma = *(const int4*)&adj[i * N + jb];
        int4 mb = *(const int4*)&adj[i * N + jb + 4];
        float e[8]; int mm[8];
        e[0]=s1i+sa.x; e[1]=s1i+sa.y; e[2]=s1i+sa.z; e[3]=s1i+sa.w;
        e[4]=s1i+sb.x; e[5]=s1i+sb.y; e[6]=s1i+sb.z; e[7]=s1i+sb.w;
        mm[0]=ma.x; mm[1]=ma.y; mm[2]=ma.z; mm[3]=ma.w;
        mm[4]=mb.x; mm[5]=mb.y; mm[6]=mb.z; mm[7]=mb.w;
        float mx = -3e38f;
        #pragma unroll
        for (int q = 0; q < 8; q++) {
            e[q] = e[q] > 0.f ? e[q] : LEAK * e[q];
            if (mm[q] > 0) mx = fmaxf(mx, e[q]);
        }
        #pragma unroll
        for (int off = 32; off > 0; off >>= 1) mx = fmaxf(mx, __shfl_xor(mx, off));
        int wid = tid >> 6, lane = tid & 63;
        if (lane == 0) red[wid] = mx;
        __syncthreads();
        mx = fmaxf(red[2 * r], red[2 * r + 1]);
        float ev[8]; float sum = 0.f;
        #pragma unroll
        for (int q = 0; q < 8; q++) {
            ev[q] = (mm[q] > 0) ? __expf(e[q] - mx) : 0.f;
            sum += ev[q];
        }
        #pragma unroll
        for (int off = 32; off > 0; off >>= 1) sum += __shfl_xor(sum, off);
        if (lane == 0) red2[wid] = sum;
        __syncthreads();
        sum = red2[2 * r] + red2[2 * r + 1];
        float inv = sum > 0.f ? 1.f / sum : 0.f;
        *(float4*)&al[r][jb]     = make_float4(ev[0]*inv, ev[1]*inv, ev[2]*inv, ev[3]*inv);
        *(float4*)&al[r][jb + 4] = make_float4(ev[4]*inv, ev[5]*inv, ev[6]*inv, ev[7]*inv);
        if ((tid & 127) == 0) gsum[r] = sum;
    }
    __syncthreads();   // al + gsum visible; no further barriers until epilogue

    const int l32 = tid & 31, g = tid >> 5;       // 16 groups x 32 lanes
    const int k0 = l32 * 4;
    const float4 wp = *(const float4*)&wpd[k0];
    const float4 wu = *(const float4*)&wut[k0];

    const float* pdb = pd + (size_t)i0 * N;
    const float* utb = ut + (size_t)i0 * N;

    float4 acc[MROWS] = {};

    for (int c = 0; c < 64; c++) {
        int j = c * 16 + g;
        float4 b0 = *(const float4*)&base[j * D + k0];
        #pragma unroll
        for (int r = 0; r < MROWS; r++) {
            float spd = pdb[r * N + j];
            float sut = utb[r * N + j];
            float sal = al[r][j];
            float v;
            v = fmaxf(fmaf(spd, wp.x, fmaf(sut, wu.x, b0.x)), 0.f); acc[r].x = fmaf(sal, v, acc[r].x);
            v = fmaxf(fmaf(spd, wp.y, fmaf(sut, wu.y, b0.y)), 0.f); acc[r].y = fmaf(sal, v, acc[r].y);
            v = fmaxf(fmaf(spd, wp.z, fmaf(sut, wu.z, b0.z)), 0.f); acc[r].z = fmaf(sal, v, acc[r].z);
            v = fmaxf(fmaf(spd, wp.w, fmaf(sut, wu.w, b0.w)), 0.f); acc[r].w = fmaf(sal, v, acc[r].w);
        }
    }

    // ---- fold the wave's two groups (lanes l <-> l^32 share k0) ----
    #pragma unroll
    for (int r = 0; r < MROWS; r++) {
        acc[r].x += __shfl_xor(acc[r].x, 32);
        acc[r].y += __shfl_xor(acc[r].y, 32);
        acc[r].z += __shfl_xor(acc[r].z, 32);
        acc[r].w += __shfl_xor(acc[r].w, 32);
    }
    {
        int w = tid >> 6, lane = tid & 63;
        if (lane < 32) {
            #pragma unroll
            for (int r = 0; r < MROWS; r++)
                *(float4*)&racc[w][r][k0] = acc[r];
        }
    }
    __syncthreads();
    {
        int rr = tid >> 7, k = tid & 127;
        float v = 0.f;
        #pragma unroll
        for (int w = 0; w < 8; w++) v += racc[w][rr][k];
        tl[rr][k] = v;
    }
    __syncthreads();
    // ---- final GEMM: out[i][d] = sum_k t[k] * W2t[k][d] + gate*b2[d] ----
    {
        int rr = tid >> 7, d = tid & 127;
        float acc2 = (gsum[rr] > 0.f) ? b2[d] : 0.f;
        #pragma unroll 8
        for (int k = 0; k < D; k++)
            acc2 = fmaf(tl[rr][k], W2t[k * D + d], acc2);
        out[(i0 + rr) * D + d] = acc2;
    }
}

// ---------------------------------------------------------------------------
extern "C" void kernel_launch(void* const* d_in, const int* in_sizes, int n_in,
                              void* d_out, int out_size, void* d_ws, size_t ws_size,
                              hipStream_t stream) {
    (void)in_sizes; (void)n_in; (void)out_size; (void)ws_size;
    const float* h   = (const float*)d_in[0];
    const int*   adj = (const int*)d_in[1];
    const float* pd  = (const float*)d_in[2];
    const float* ut  = (const float*)d_in[3];
    const float* W   = (const float*)d_in[4];
    const float* a   = (const float*)d_in[5];
    const float* W1  = (const float*)d_in[6];
    const float* b1  = (const float*)d_in[7];
    const float* W2  = (const float*)d_in[8];
    const float* b2  = (const float*)d_in[9];
    float* out = (float*)d_out;
    float* ws = (float*)d_ws;

    float* W2t   = ws + OFF_W2T;
    float* wpd   = ws + OFF_WPD;
    float* wut   = ws + OFF_WUT;
    float* s1    = ws + OFF_S1;
    float* s2    = ws + OFF_S2;
    float* baseb = ws + OFF_BASE;

    prep_base_kernel<<<517, 256, 0, stream>>>(W, W1, W2, a, h, b1,
                                              W2t, wpd, wut, s1, s2, baseb);
    mega_kernel<<<N / MROWS, 512, 0, stream>>>(baseb, s1, s2, adj, pd, ut,
                                               wpd, wut, W2t, b2, out);
}